// Round 5
// baseline (165.222 us; speedup 1.0000x reference)
//
#include <hip/hip_runtime.h>

#define R 256
#define T 32

#define TILE 32
#define XW 36           // x-tile extent (halo 2 each side)
#define HROWS 34        // hidden rows  (-1..32) -> hs row 0..33 (= hidden row + 1)
#define HSTR 36         // hidden row stride in words (hs col = hidden col + 1)
#define CP 1232         // channel plane stride words (34*36=1224 +8; %4=0 keeps 16B align)

// ---------------------------------------------------------------------------
// Kernel A (unchanged — known-good from R3)
// ---------------------------------------------------------------------------
__global__ __launch_bounds__(256) void einsum_kernel(
    const float* __restrict__ yt, const float* __restrict__ Ht,
    float* __restrict__ x) {
  const int idx = blockIdx.x;
  const int r   = idx >> 8;
  const int yy  = (idx & 255) >> 2;
  const int bq  = idx & 3;
  const int p   = yy * 4 + r;
  const int b0  = bq * 8;
  const int tid = threadIdx.x;
  const int qp  = tid & 127;
  const int bh  = tid >> 7;
  const int q4  = qp >> 1;

  __shared__ float yts[8 * 32 * 64];

#pragma unroll
  for (int i = 0; i < 16; ++i) {
    int f4  = tid + i * 256;
    int b_l = f4 >> 9;
    int t   = (f4 >> 4) & 31;
    int xx4 = f4 & 15;
    float4 v = *(const float4*)(yt + (((size_t)(b0 + b_l) * T + t) * 64 + yy) * 64 + xx4 * 4);
    *(float4*)(yts + f4 * 4) = v;
  }

  float2 ht[T];
  const float* Hp = Ht + p * R + 2 * qp;
#pragma unroll
  for (int t = 0; t < T; ++t) ht[t] = *(const float2*)(Hp + (size_t)t * R * R);

  __syncthreads();

#pragma unroll
  for (int bi = 0; bi < 4; ++bi) {
    const int b_l = bh * 4 + bi;
    const float* ys = yts + b_l * 2048 + q4;
    float ax = 0.f, ay = 0.f;
#pragma unroll
    for (int t = 0; t < T; ++t) {
      float yv = ys[t * 64];
      ax += ht[t].x * yv;
      ay += ht[t].y * yv;
    }
    float2 o = {ax, ay};
    *(float2*)(x + ((size_t)(b0 + b_l) * R + p) * R + 2 * qp) = o;
  }
}

// ---------------------------------------------------------------------------
// Kernel B: fused Conv(1->32,3x3) -> ReLU -> Conv(32->1,3x3), SAME.
// NOTE: hs is passed ONCE, non-restrict — conv1 writes and conv2 reads alias
// through the same pointer (the R4 dual-restrict version was UB).
// ---------------------------------------------------------------------------
template <bool EDGE>
__device__ __forceinline__ void conv_body(
    const float (&patch)[5][9], const bool (&slot)[5], const bool (&oob)[5],
    const int (&sw)[5], float* hs,
    const float* __restrict__ W1, const float* __restrict__ b1,
    const float* __restrict__ W2, int cl, int hboff, float (&acc)[4][4]) {
  for (int cg = 0; cg < 8; ++cg) {
    // per-lane conv2 weights for this group (issued early, consumed late)
    float w2[9];
#pragma unroll
    for (int k = 0; k < 9; ++k) w2[k] = W2[(cg * 4 + cl) * 9 + k];

    // ---- conv1 + relu: channels cg*4..cg*4+3 into planes 0..3 ----
#pragma unroll
    for (int c = 0; c < 4; ++c) {
      const int ch = cg * 4 + c;            // wave-uniform -> SGPR weights
      const float bias = b1[ch];
#pragma unroll
      for (int it = 0; it < 5; ++it) {
        if (slot[it]) {
          float h = bias;
#pragma unroll
          for (int k = 0; k < 9; ++k) h += W1[ch * 9 + k] * patch[it][k];
          h = fmaxf(h, 0.f);
          if (EDGE) {
            if (oob[it]) h = 0.f;          // conv2 SAME: outside image = 0
          }
          hs[c * CP + sw[it]] = h;         // imm-offset ds_write
        }
      }
    }
    __syncthreads();

    // ---- conv2 partials: 6 rolling rows, each read once ----
#pragma unroll
    for (int j = 0; j < 6; ++j) {
      float4 v4 = *(const float4*)(hs + hboff + j * HSTR);
      float2 v2 = *(const float2*)(hs + hboff + j * HSTR + 4);
      float v[6] = {v4.x, v4.y, v4.z, v4.w, v2.x, v2.y};
#pragma unroll
      for (int dy = 0; dy < 3; ++dy) {
        int ai = j - dy;
        if (ai >= 0 && ai < 4) {
#pragma unroll
          for (int dx = 0; dx < 3; ++dx) {
            const float w = w2[dy * 3 + dx];
#pragma unroll
            for (int px = 0; px < 4; ++px) acc[ai][px] += w * v[px + dx];
          }
        }
      }
    }
    __syncthreads();
  }
}

__global__ __launch_bounds__(256, 5) void conv_fused_kernel(
    const float* __restrict__ x, const float* __restrict__ W1,
    const float* __restrict__ b1, const float* __restrict__ W2,
    const float* __restrict__ b2, float* __restrict__ out) {
  __shared__ float xs[XW * XW];   // 5184 B
  __shared__ float hs[4 * CP];    // 19712 B

  const int tid  = threadIdx.x;
  const int b    = blockIdx.x >> 6;
  const int tile = blockIdx.x & 63;
  const int oy0  = (tile >> 3) * TILE;
  const int ox0  = (tile & 7) * TILE;
  const float* xb = x + (size_t)b * R * R;

  // --- stage x tile with halo 2, zero-padded ---
  for (int i = tid; i < XW * XW; i += 256) {
    int rr = i / XW, cc = i % XW;
    int gy = oy0 - 2 + rr, gx = ox0 - 2 + cc;
    float v = 0.f;
    if (gy >= 0 && gy < R && gx >= 0 && gx < R) v = xb[gy * R + gx];
    xs[i] = v;
  }
  __syncthreads();

  // --- per-thread 3x3 patches for its 34x34-grid hidden slots ---
  float patch[5][9];
  int  sw[5];
  bool slot[5], oob[5];
#pragma unroll
  for (int it = 0; it < 5; ++it) {
    int px = tid + it * 256;
    slot[it] = (px < HROWS * HROWS);     // 1156
    int hy = slot[it] ? (px / 34) : 0;
    int hx = slot[it] ? (px % 34) : 0;
    sw[it] = hy * HSTR + hx;
    int ghy = oy0 - 1 + hy, ghx = ox0 - 1 + hx;
    oob[it] = !((ghy >= 0) & (ghy < R) & (ghx >= 0) & (ghx < R));
#pragma unroll
    for (int ky = 0; ky < 3; ++ky)
#pragma unroll
      for (int kx = 0; kx < 3; ++kx)
        patch[it][ky * 3 + kx] = slot[it] ? xs[(hy + ky) * XW + hx + kx] : 0.f;
  }

  const int wv   = tid >> 6;          // wave: out rows 8wv..8wv+7
  const int lane = tid & 63;
  const int g    = lane & 7;          // col granule: px 4g..4g+3
  const int cl   = (lane >> 3) & 3;   // channel in group
  const int rh   = lane >> 5;         // row half
  const int r0   = 8 * wv + 4 * rh;   // first out row of this lane

  float acc[4][4];
#pragma unroll
  for (int ai = 0; ai < 4; ++ai)
#pragma unroll
    for (int px = 0; px < 4; ++px) acc[ai][px] = 0.f;

  const int hboff = cl * CP + r0 * HSTR + 4 * g;

  const bool edge = (oy0 == 0) | (oy0 == R - TILE) | (ox0 == 0) | (ox0 == R - TILE);
  if (edge)
    conv_body<true>(patch, slot, oob, sw, hs, W1, b1, W2, cl, hboff, acc);
  else
    conv_body<false>(patch, slot, oob, sw, hs, W1, b1, W2, cl, hboff, acc);

  // ---- reduce over the 4 channels (lane xor 8,16) and store ----
  const float bias2 = b2[0];
#pragma unroll
  for (int ai = 0; ai < 4; ++ai)
#pragma unroll
    for (int px = 0; px < 4; ++px) {
      float v = acc[ai][px];
      v += __shfl_xor(v, 8);
      v += __shfl_xor(v, 16);
      acc[ai][px] = v;
    }
  if (cl == 0) {
#pragma unroll
    for (int ai = 0; ai < 4; ++ai) {
      float4 o = {acc[ai][0] + bias2, acc[ai][1] + bias2,
                  acc[ai][2] + bias2, acc[ai][3] + bias2};
      *(float4*)(out + (size_t)b * R * R + (oy0 + r0 + ai) * R + ox0 + 4 * g) = o;
    }
  }
}

// ---------------------------------------------------------------------------
extern "C" void kernel_launch(void* const* d_in, const int* in_sizes, int n_in,
                              void* d_out, int out_size, void* d_ws, size_t ws_size,
                              hipStream_t stream) {
  const float* yt = (const float*)d_in[0];  // (32,32,64,64)
  const float* Ht = (const float*)d_in[1];  // (32,256,256)
  const float* W1 = (const float*)d_in[2];  // (32,1,3,3)
  const float* b1 = (const float*)d_in[3];  // (32,)
  const float* W2 = (const float*)d_in[4];  // (1,32,3,3)
  const float* b2 = (const float*)d_in[5];  // (1,)
  float* outp = (float*)d_out;              // (32,1,256,256)
  float* x    = (float*)d_ws;               // 8 MB scratch

  einsum_kernel<<<1024, 256, 0, stream>>>(yt, Ht, x);
  conv_fused_kernel<<<2048, 256, 0, stream>>>(x, W1, b1, W2, b2, outp);
}

// Round 6
// 154.820 us; speedup vs baseline: 1.0672x; 1.0672x over previous
//
#include <hip/hip_runtime.h>

#define R 256
#define T 32

#define TILE 32
#define XW 36           // x-tile extent (halo 2 each side)
#define HROWS 34        // hidden rows  (-1..32) -> hs row 0..33 (= hidden row + 1)
#define HSTR 36         // hidden row stride in words (hs col = hidden col + 1)
#define CP 1240         // channel plane stride words: %32=24 -> cl bank offsets {0,24,16,8} distinct; %4=0 keeps 16B align

// ---------------------------------------------------------------------------
// Kernel A (unchanged — known-good from R3)
// ---------------------------------------------------------------------------
__global__ __launch_bounds__(256) void einsum_kernel(
    const float* __restrict__ yt, const float* __restrict__ Ht,
    float* __restrict__ x) {
  const int idx = blockIdx.x;
  const int r   = idx >> 8;
  const int yy  = (idx & 255) >> 2;
  const int bq  = idx & 3;
  const int p   = yy * 4 + r;
  const int b0  = bq * 8;
  const int tid = threadIdx.x;
  const int qp  = tid & 127;
  const int bh  = tid >> 7;
  const int q4  = qp >> 1;

  __shared__ float yts[8 * 32 * 64];

#pragma unroll
  for (int i = 0; i < 16; ++i) {
    int f4  = tid + i * 256;
    int b_l = f4 >> 9;
    int t   = (f4 >> 4) & 31;
    int xx4 = f4 & 15;
    float4 v = *(const float4*)(yt + (((size_t)(b0 + b_l) * T + t) * 64 + yy) * 64 + xx4 * 4);
    *(float4*)(yts + f4 * 4) = v;
  }

  float2 ht[T];
  const float* Hp = Ht + p * R + 2 * qp;
#pragma unroll
  for (int t = 0; t < T; ++t) ht[t] = *(const float2*)(Hp + (size_t)t * R * R);

  __syncthreads();

#pragma unroll
  for (int bi = 0; bi < 4; ++bi) {
    const int b_l = bh * 4 + bi;
    const float* ys = yts + b_l * 2048 + q4;
    float ax = 0.f, ay = 0.f;
#pragma unroll
    for (int t = 0; t < T; ++t) {
      float yv = ys[t * 64];
      ax += ht[t].x * yv;
      ay += ht[t].y * yv;
    }
    float2 o = {ax, ay};
    *(float2*)(x + ((size_t)(b0 + b_l) * R + p) * R + 2 * qp) = o;
  }
}

// ---------------------------------------------------------------------------
// Kernel B: fused Conv(1->32,3x3) -> ReLU -> Conv(32->1,3x3), SAME.
// hs passed ONCE, non-restrict (conv1 writes / conv2 reads alias legally).
// NO second launch_bounds arg: R5's (256,5) forced 48 VGPRs and spilled
// patch[5][9] to scratch (+32 MB HBM writes). Compiler picks ~84 -> 6 wv/EU.
// ---------------------------------------------------------------------------
template <bool EDGE>
__device__ __forceinline__ void conv_body(
    const float (&patch)[5][9], const bool (&slot)[5], const bool (&oob)[5],
    const int (&sw)[5], float* hs,
    const float* __restrict__ W1, const float* __restrict__ b1,
    const float* __restrict__ W2, int cl, int hboff, float (&acc)[4][4]) {
  for (int cg = 0; cg < 8; ++cg) {
    // per-lane conv2 weights for this group (issued early, consumed late)
    float w2[9];
#pragma unroll
    for (int k = 0; k < 9; ++k) w2[k] = W2[(cg * 4 + cl) * 9 + k];

    // ---- conv1 + relu: channels cg*4..cg*4+3 into planes 0..3 ----
#pragma unroll
    for (int c = 0; c < 4; ++c) {
      const int ch = cg * 4 + c;            // wave-uniform -> SGPR weights
      const float bias = b1[ch];
#pragma unroll
      for (int it = 0; it < 5; ++it) {
        if (slot[it]) {
          float h = bias;
#pragma unroll
          for (int k = 0; k < 9; ++k) h += W1[ch * 9 + k] * patch[it][k];
          h = fmaxf(h, 0.f);
          if (EDGE) {
            if (oob[it]) h = 0.f;          // conv2 SAME: outside image = 0
          }
          hs[c * CP + sw[it]] = h;         // imm-offset ds_write
        }
      }
    }
    __syncthreads();

    // ---- conv2 partials: 6 rolling rows, each read once ----
#pragma unroll
    for (int j = 0; j < 6; ++j) {
      float4 v4 = *(const float4*)(hs + hboff + j * HSTR);
      float2 v2 = *(const float2*)(hs + hboff + j * HSTR + 4);
      float v[6] = {v4.x, v4.y, v4.z, v4.w, v2.x, v2.y};
#pragma unroll
      for (int dy = 0; dy < 3; ++dy) {
        int ai = j - dy;
        if (ai >= 0 && ai < 4) {
#pragma unroll
          for (int dx = 0; dx < 3; ++dx) {
            const float w = w2[dy * 3 + dx];
#pragma unroll
            for (int px = 0; px < 4; ++px) acc[ai][px] += w * v[px + dx];
          }
        }
      }
    }
    __syncthreads();
  }
}

__global__ __launch_bounds__(256) void conv_fused_kernel(
    const float* __restrict__ x, const float* __restrict__ W1,
    const float* __restrict__ b1, const float* __restrict__ W2,
    const float* __restrict__ b2, float* __restrict__ out) {
  __shared__ float xs[XW * XW];   // 5184 B
  __shared__ float hs[4 * CP];    // 19840 B

  const int tid  = threadIdx.x;
  const int b    = blockIdx.x >> 6;
  const int tile = blockIdx.x & 63;
  const int oy0  = (tile >> 3) * TILE;
  const int ox0  = (tile & 7) * TILE;
  const float* xb = x + (size_t)b * R * R;

  // --- stage x tile with halo 2, zero-padded ---
  for (int i = tid; i < XW * XW; i += 256) {
    int rr = i / XW, cc = i % XW;
    int gy = oy0 - 2 + rr, gx = ox0 - 2 + cc;
    float v = 0.f;
    if (gy >= 0 && gy < R && gx >= 0 && gx < R) v = xb[gy * R + gx];
    xs[i] = v;
  }
  __syncthreads();

  // --- per-thread 3x3 patches for its 34x34-grid hidden slots ---
  float patch[5][9];
  int  sw[5];
  bool slot[5], oob[5];
#pragma unroll
  for (int it = 0; it < 5; ++it) {
    int px = tid + it * 256;
    slot[it] = (px < HROWS * HROWS);     // 1156
    int hy = slot[it] ? (px / 34) : 0;
    int hx = slot[it] ? (px % 34) : 0;
    sw[it] = hy * HSTR + hx;
    int ghy = oy0 - 1 + hy, ghx = ox0 - 1 + hx;
    oob[it] = !((ghy >= 0) & (ghy < R) & (ghx >= 0) & (ghx < R));
#pragma unroll
    for (int ky = 0; ky < 3; ++ky)
#pragma unroll
      for (int kx = 0; kx < 3; ++kx)
        patch[it][ky * 3 + kx] = slot[it] ? xs[(hy + ky) * XW + hx + kx] : 0.f;
  }

  const int wv   = tid >> 6;          // wave: out rows 8wv..8wv+7
  const int lane = tid & 63;
  const int g    = lane & 7;          // col granule: px 4g..4g+3
  const int cl   = (lane >> 3) & 3;   // channel in group
  const int rh   = lane >> 5;         // row half
  const int r0   = 8 * wv + 4 * rh;   // first out row of this lane

  float acc[4][4];
#pragma unroll
  for (int ai = 0; ai < 4; ++ai)
#pragma unroll
    for (int px = 0; px < 4; ++px) acc[ai][px] = 0.f;

  const int hboff = cl * CP + r0 * HSTR + 4 * g;

  const bool edge = (oy0 == 0) | (oy0 == R - TILE) | (ox0 == 0) | (ox0 == R - TILE);
  if (edge)
    conv_body<true>(patch, slot, oob, sw, hs, W1, b1, W2, cl, hboff, acc);
  else
    conv_body<false>(patch, slot, oob, sw, hs, W1, b1, W2, cl, hboff, acc);

  // ---- reduce over the 4 channels (lane xor 8,16) and store ----
  const float bias2 = b2[0];
#pragma unroll
  for (int ai = 0; ai < 4; ++ai)
#pragma unroll
    for (int px = 0; px < 4; ++px) {
      float v = acc[ai][px];
      v += __shfl_xor(v, 8);
      v += __shfl_xor(v, 16);
      acc[ai][px] = v;
    }
  if (cl == 0) {
#pragma unroll
    for (int ai = 0; ai < 4; ++ai) {
      float4 o = {acc[ai][0] + bias2, acc[ai][1] + bias2,
                  acc[ai][2] + bias2, acc[ai][3] + bias2};
      *(float4*)(out + (size_t)b * R * R + (oy0 + r0 + ai) * R + ox0 + 4 * g) = o;
    }
  }
}

// ---------------------------------------------------------------------------
extern "C" void kernel_launch(void* const* d_in, const int* in_sizes, int n_in,
                              void* d_out, int out_size, void* d_ws, size_t ws_size,
                              hipStream_t stream) {
  const float* yt = (const float*)d_in[0];  // (32,32,64,64)
  const float* Ht = (const float*)d_in[1];  // (32,256,256)
  const float* W1 = (const float*)d_in[2];  // (32,1,3,3)
  const float* b1 = (const float*)d_in[3];  // (32,)
  const float* W2 = (const float*)d_in[4];  // (1,32,3,3)
  const float* b2 = (const float*)d_in[5];  // (1,)
  float* outp = (float*)d_out;              // (32,1,256,256)
  float* x    = (float*)d_ws;               // 8 MB scratch

  einsum_kernel<<<1024, 256, 0, stream>>>(yt, Ht, x);
  conv_fused_kernel<<<2048, 256, 0, stream>>>(x, W1, b1, W2, b2, outp);
}

// Round 7
// 140.554 us; speedup vs baseline: 1.1755x; 1.1015x over previous
//
#include <hip/hip_runtime.h>

#define R 256
#define T 32

#define TROWS 16        // out tile rows
#define TCOLS 32        // out tile cols
#define XROWS 20        // x tile rows (halo 2)
#define XCOLS 36        // x tile cols (halo 2)
#define HR 18           // hidden rows stored (out rows + halo 1)
#define HC 34           // hidden cols stored (out cols + halo 1)
#define HSTR 36         // hidden row stride (words); hs col = hidden col + 1
#define CP 648          // plane stride words = 18*36; %32=8 -> cl bank offsets {0,8,16,24}; %4==0
#define NPX (HR * HC)   // 612 hidden px per tile

// ---------------------------------------------------------------------------
// Kernel A (unchanged — known-good since R3)
// ---------------------------------------------------------------------------
__global__ __launch_bounds__(256) void einsum_kernel(
    const float* __restrict__ yt, const float* __restrict__ Ht,
    float* __restrict__ x) {
  const int idx = blockIdx.x;
  const int r   = idx >> 8;
  const int yy  = (idx & 255) >> 2;
  const int bq  = idx & 3;
  const int p   = yy * 4 + r;
  const int b0  = bq * 8;
  const int tid = threadIdx.x;
  const int qp  = tid & 127;
  const int bh  = tid >> 7;
  const int q4  = qp >> 1;

  __shared__ float yts[8 * 32 * 64];

#pragma unroll
  for (int i = 0; i < 16; ++i) {
    int f4  = tid + i * 256;
    int b_l = f4 >> 9;
    int t   = (f4 >> 4) & 31;
    int xx4 = f4 & 15;
    float4 v = *(const float4*)(yt + (((size_t)(b0 + b_l) * T + t) * 64 + yy) * 64 + xx4 * 4);
    *(float4*)(yts + f4 * 4) = v;
  }

  float2 ht[T];
  const float* Hp = Ht + p * R + 2 * qp;
#pragma unroll
  for (int t = 0; t < T; ++t) ht[t] = *(const float2*)(Hp + (size_t)t * R * R);

  __syncthreads();

#pragma unroll
  for (int bi = 0; bi < 4; ++bi) {
    const int b_l = bh * 4 + bi;
    const float* ys = yts + b_l * 2048 + q4;
    float ax = 0.f, ay = 0.f;
#pragma unroll
    for (int t = 0; t < T; ++t) {
      float yv = ys[t * 64];
      ax += ht[t].x * yv;
      ay += ht[t].y * yv;
    }
    float2 o = {ax, ay};
    *(float2*)(x + ((size_t)(b0 + b_l) * R + p) * R + 2 * qp) = o;
  }
}

// ---------------------------------------------------------------------------
// Kernel B: fused Conv(1->32,3x3) -> ReLU -> Conv(32->1,3x3), SAME.
// 128-thread (2-wave) blocks, 16x32 tiles: barriers sync only 2 waves and
// LDS (13.2 KB) allows ~12 blocks/CU so other blocks cover the drains.
// hs passed non-restrict (conv1 writes / conv2 reads alias legally).
// ---------------------------------------------------------------------------
template <bool EDGE>
__device__ __forceinline__ void conv_body(
    const float (&patch)[5][9], bool slot4, const bool (&oob)[5],
    const int (&sw)[5], float* hs,
    const float* __restrict__ W1, const float* __restrict__ b1,
    const float* __restrict__ W2, int cl, int hboff, float (&acc)[4][4]) {
  for (int cg = 0; cg < 8; ++cg) {
    // per-lane conv2 weights for this group (issued early, consumed late)
    float w2[9];
#pragma unroll
    for (int k = 0; k < 9; ++k) w2[k] = W2[(cg * 4 + cl) * 9 + k];

    // ---- conv1 + relu: channels cg*4..cg*4+3 into planes 0..3 ----
#pragma unroll
    for (int c = 0; c < 4; ++c) {
      const int ch = cg * 4 + c;            // wave-uniform -> SGPR weights
      const float bias = b1[ch];
#pragma unroll
      for (int it = 0; it < 5; ++it) {
        if (it < 4 || slot4) {              // slots 0..3 statically full
          float h = bias;
#pragma unroll
          for (int k = 0; k < 9; ++k) h += W1[ch * 9 + k] * patch[it][k];
          h = fmaxf(h, 0.f);
          if (EDGE) {
            if (oob[it]) h = 0.f;          // conv2 SAME: outside image = 0
          }
          hs[c * CP + sw[it]] = h;
        }
      }
    }
    __syncthreads();

    // ---- conv2 partials: 6 rolling rows, each read once ----
#pragma unroll
    for (int j = 0; j < 6; ++j) {
      float4 v4 = *(const float4*)(hs + hboff + j * HSTR);
      float2 v2 = *(const float2*)(hs + hboff + j * HSTR + 4);
      float v[6] = {v4.x, v4.y, v4.z, v4.w, v2.x, v2.y};
#pragma unroll
      for (int dy = 0; dy < 3; ++dy) {
        int ai = j - dy;
        if (ai >= 0 && ai < 4) {
#pragma unroll
          for (int dx = 0; dx < 3; ++dx) {
            const float w = w2[dy * 3 + dx];
#pragma unroll
            for (int px = 0; px < 4; ++px) acc[ai][px] += w * v[px + dx];
          }
        }
      }
    }
    __syncthreads();
  }
}

__global__ __launch_bounds__(128) void conv_fused_kernel(
    const float* __restrict__ x, const float* __restrict__ W1,
    const float* __restrict__ b1, const float* __restrict__ W2,
    const float* __restrict__ b2, float* __restrict__ out) {
  __shared__ float xs[XROWS * XCOLS];  // 2880 B
  __shared__ float hs[4 * CP];         // 10368 B

  const int tid  = threadIdx.x;
  const int b    = blockIdx.x >> 7;
  const int tile = blockIdx.x & 127;
  const int oy0  = (tile >> 3) * TROWS;   // 0..240
  const int ox0  = (tile & 7) * TCOLS;    // 0..224
  const float* xb = x + (size_t)b * R * R;

  // --- stage x tile with halo 2, zero-padded ---
  for (int i = tid; i < XROWS * XCOLS; i += 128) {
    int rr = i / XCOLS, cc = i % XCOLS;
    int gy = oy0 - 2 + rr, gx = ox0 - 2 + cc;
    float v = 0.f;
    if (gy >= 0 && gy < R && gx >= 0 && gx < R) v = xb[gy * R + gx];
    xs[i] = v;
  }
  __syncthreads();

  // --- per-thread 3x3 patches for its hidden slots (18x34 grid, 612 px) ---
  float patch[5][9];
  int  sw[5];
  bool oob[5];
  const bool slot4 = (tid < NPX - 4 * 128);   // 100
#pragma unroll
  for (int it = 0; it < 5; ++it) {
    int px = tid + it * 128;
    bool act = (it < 4) || slot4;
    int hy = act ? (px / HC) : 0;
    int hx = act ? (px % HC) : 0;
    sw[it] = hy * HSTR + hx;
    int ghy = oy0 - 1 + hy, ghx = ox0 - 1 + hx;
    oob[it] = !((ghy >= 0) & (ghy < R) & (ghx >= 0) & (ghx < R));
#pragma unroll
    for (int ky = 0; ky < 3; ++ky)
#pragma unroll
      for (int kx = 0; kx < 3; ++kx)
        patch[it][ky * 3 + kx] = act ? xs[(hy + ky) * XCOLS + hx + kx] : 0.f;
  }

  const int g  = tid & 7;          // col granule: px 4g..4g+3
  const int cl = (tid >> 3) & 3;   // channel in group (in-wave bits 3-4)
  const int rh = tid >> 5;         // 0..3: out rows 4rh..4rh+3
  const int r0 = 4 * rh;

  float acc[4][4];
#pragma unroll
  for (int ai = 0; ai < 4; ++ai)
#pragma unroll
    for (int px = 0; px < 4; ++px) acc[ai][px] = 0.f;

  const int hboff = cl * CP + r0 * HSTR + 4 * g;

  const bool edge = (oy0 == 0) | (oy0 == R - TROWS) | (ox0 == 0) | (ox0 == R - TCOLS);
  if (edge)
    conv_body<true>(patch, slot4, oob, sw, hs, W1, b1, W2, cl, hboff, acc);
  else
    conv_body<false>(patch, slot4, oob, sw, hs, W1, b1, W2, cl, hboff, acc);

  // ---- reduce over the 4 channels (lane xor 8,16) and store ----
  const float bias2 = b2[0];
#pragma unroll
  for (int ai = 0; ai < 4; ++ai)
#pragma unroll
    for (int px = 0; px < 4; ++px) {
      float v = acc[ai][px];
      v += __shfl_xor(v, 8);
      v += __shfl_xor(v, 16);
      acc[ai][px] = v;
    }
  if (cl == 0) {
#pragma unroll
    for (int ai = 0; ai < 4; ++ai) {
      float4 o = {acc[ai][0] + bias2, acc[ai][1] + bias2,
                  acc[ai][2] + bias2, acc[ai][3] + bias2};
      *(float4*)(out + (size_t)b * R * R + (oy0 + r0 + ai) * R + ox0 + 4 * g) = o;
    }
  }
}

// ---------------------------------------------------------------------------
extern "C" void kernel_launch(void* const* d_in, const int* in_sizes, int n_in,
                              void* d_out, int out_size, void* d_ws, size_t ws_size,
                              hipStream_t stream) {
  const float* yt = (const float*)d_in[0];  // (32,32,64,64)
  const float* Ht = (const float*)d_in[1];  // (32,256,256)
  const float* W1 = (const float*)d_in[2];  // (32,1,3,3)
  const float* b1 = (const float*)d_in[3];  // (32,)
  const float* W2 = (const float*)d_in[4];  // (1,32,3,3)
  const float* b2 = (const float*)d_in[5];  // (1,)
  float* outp = (float*)d_out;              // (32,1,256,256)
  float* x    = (float*)d_ws;               // 8 MB scratch

  einsum_kernel<<<1024, 256, 0, stream>>>(yt, Ht, x);
  conv_fused_kernel<<<4096, 128, 0, stream>>>(x, W1, b1, W2, b2, outp);
}